// Round 1
// baseline (3363.605 us; speedup 1.0000x reference)
//
#include <hip/hip_runtime.h>

#define BB   128
#define TT   256
#define CC   384
#define HH   6
#define HSZ  64
#define DFF  1536
#define EPSV 1e-5f
#define RPB  8     // rows per block for the GEMV kernels

// ---------------- block-wide reduction over 384 threads (6 waves) -------------
__device__ __forceinline__ void block_reduce2(float& a, float& b, float* red) {
    #pragma unroll
    for (int off = 32; off > 0; off >>= 1) {
        a += __shfl_down(a, off, 64);
        b += __shfl_down(b, off, 64);
    }
    const int lane = threadIdx.x & 63;
    const int wid  = threadIdx.x >> 6;
    if (lane == 0) { red[wid * 2] = a; red[wid * 2 + 1] = b; }
    __syncthreads();
    if (threadIdx.x == 0) {
        float sa = 0.f, sb = 0.f;
        #pragma unroll
        for (int w = 0; w < 6; ++w) { sa += red[w * 2]; sb += red[w * 2 + 1]; }
        red[12] = sa; red[13] = sb;
    }
    __syncthreads();
    a = red[12]; b = red[13];
}

// ---------------- K1: LN1 + QKV projection ------------------------------------
// grid = (B*T)/RPB, block = 384.  Outputs q/k/v in (B,H,T,HS) layout.
__global__ __launch_bounds__(CC) void qkv_kernel(
        const float* __restrict__ x,
        const float* __restrict__ Wq, const float* __restrict__ Wk,
        const float* __restrict__ Wv,
        const float* __restrict__ g1, const float* __restrict__ be1,
        float* __restrict__ qb, float* __restrict__ kb, float* __restrict__ vb) {
    __shared__ float hn[RPB][CC];
    __shared__ float red[16];
    const int tid = threadIdx.x;
    const long row0 = (long)blockIdx.x * RPB;

    for (int r = 0; r < RPB; ++r) {
        float v = x[(row0 + r) * CC + tid];
        float s = v, sq = v * v;
        block_reduce2(s, sq, red);
        float mu  = s  * (1.0f / CC);
        float var = sq * (1.0f / CC) - mu * mu;
        float rs  = rsqrtf(var + EPSV);
        hn[r][tid] = (v - mu) * rs * g1[tid] + be1[tid];
        __syncthreads();
    }

    const int hh = tid >> 6, d = tid & 63;
    const float* wqp = Wq + (long)hh * CC * HSZ + d;
    const float* wkp = Wk + (long)hh * CC * HSZ + d;
    const float* wvp = Wv + (long)hh * CC * HSZ + d;

    float aq[RPB], ak[RPB], av[RPB];
    #pragma unroll
    for (int r = 0; r < RPB; ++r) { aq[r] = 0.f; ak[r] = 0.f; av[r] = 0.f; }

    for (int c0 = 0; c0 < CC; c0 += 4) {
        float wq[4], wk_[4], wv[4];
        #pragma unroll
        for (int i = 0; i < 4; ++i) {
            wq[i]  = wqp[(long)(c0 + i) * HSZ];
            wk_[i] = wkp[(long)(c0 + i) * HSZ];
            wv[i]  = wvp[(long)(c0 + i) * HSZ];
        }
        #pragma unroll
        for (int r = 0; r < RPB; ++r) {
            const float4 h4 = *(const float4*)&hn[r][c0];
            aq[r] = fmaf(h4.x, wq[0],  fmaf(h4.y, wq[1],  fmaf(h4.z, wq[2],  fmaf(h4.w, wq[3],  aq[r]))));
            ak[r] = fmaf(h4.x, wk_[0], fmaf(h4.y, wk_[1], fmaf(h4.z, wk_[2], fmaf(h4.w, wk_[3], ak[r]))));
            av[r] = fmaf(h4.x, wv[0],  fmaf(h4.y, wv[1],  fmaf(h4.z, wv[2],  fmaf(h4.w, wv[3],  av[r]))));
        }
    }

    const int b  = (int)(row0 / TT);
    const int t0 = (int)(row0 % TT);
    const long base = ((long)(b * HH + hh) * TT) * HSZ + d;
    #pragma unroll
    for (int r = 0; r < RPB; ++r) {
        const long idx = base + (long)(t0 + r) * HSZ;
        qb[idx] = aq[r]; kb[idx] = ak[r]; vb[idx] = av[r];
    }
}

// ---------------- K2: causal flash attention ----------------------------------
// grid = B*H, block = T(=256); thread t owns query row t.
__global__ __launch_bounds__(TT) void attn_kernel(
        const float* __restrict__ qb, const float* __restrict__ kb,
        const float* __restrict__ vb, float* __restrict__ ab) {
    __shared__ float Kt[64][64];
    __shared__ float Vt[64][64];
    const int t  = threadIdx.x;
    const int bh = blockIdx.x;

    const float4* qp = (const float4*)(qb + ((long)bh * TT + t) * HSZ);
    float4 qv[16], ov[16];
    #pragma unroll
    for (int i = 0; i < 16; ++i) { qv[i] = qp[i]; ov[i] = make_float4(0.f, 0.f, 0.f, 0.f); }

    float m = -1e30f, l = 0.f;

    for (int s0 = 0; s0 < TT; s0 += 64) {
        __syncthreads();
        {   // cooperative tile load, 16B/lane coalesced
            const float4* ks = (const float4*)(kb + (long)bh * TT * HSZ + (long)s0 * HSZ);
            const float4* vs = (const float4*)(vb + (long)bh * TT * HSZ + (long)s0 * HSZ);
            float4* kd = (float4*)&Kt[0][0];
            float4* vd = (float4*)&Vt[0][0];
            for (int i = t; i < 64 * 64 / 4; i += TT) { kd[i] = ks[i]; vd[i] = vs[i]; }
        }
        __syncthreads();

        int ns = t - s0 + 1;
        if (ns > 64) ns = 64;
        for (int si = 0; si < ns; ++si) {
            const float4* krow = (const float4*)&Kt[si][0];
            float d0 = 0.f, d1 = 0.f, d2 = 0.f, d3 = 0.f;
            #pragma unroll
            for (int i = 0; i < 16; ++i) {
                float4 kk = krow[i];
                d0 = fmaf(qv[i].x, kk.x, d0);
                d1 = fmaf(qv[i].y, kk.y, d1);
                d2 = fmaf(qv[i].z, kk.z, d2);
                d3 = fmaf(qv[i].w, kk.w, d3);
            }
            const float sc = (d0 + d1 + d2 + d3) * 0.125f;
            if (sc > m) {                       // rare rescale
                const float alpha = __expf(m - sc);
                l *= alpha;
                #pragma unroll
                for (int i = 0; i < 16; ++i) {
                    ov[i].x *= alpha; ov[i].y *= alpha;
                    ov[i].z *= alpha; ov[i].w *= alpha;
                }
                m = sc;
            }
            const float p = __expf(sc - m);
            l += p;
            const float4* vrow = (const float4*)&Vt[si][0];
            #pragma unroll
            for (int i = 0; i < 16; ++i) {
                float4 vv = vrow[i];
                ov[i].x = fmaf(p, vv.x, ov[i].x);
                ov[i].y = fmaf(p, vv.y, ov[i].y);
                ov[i].z = fmaf(p, vv.z, ov[i].z);
                ov[i].w = fmaf(p, vv.w, ov[i].w);
            }
        }
    }

    const float inv = 1.0f / l;
    const int b = bh / HH, h = bh % HH;
    float4* op = (float4*)(ab + ((long)b * TT + t) * CC + h * HSZ);
    #pragma unroll
    for (int i = 0; i < 16; ++i)
        op[i] = make_float4(ov[i].x * inv, ov[i].y * inv, ov[i].z * inv, ov[i].w * inv);
}

// ---------------- K3: output projection + residual ----------------------------
// grid = (B*T)/RPB, block = 384.  out <- x + attn @ Wo + bo   (= x2)
__global__ __launch_bounds__(CC) void proj_kernel(
        const float* __restrict__ ab, const float* __restrict__ x,
        const float* __restrict__ Wo, const float* __restrict__ bo,
        float* __restrict__ out) {
    __shared__ float at[RPB][CC];
    const int tid = threadIdx.x;
    const long row0 = (long)blockIdx.x * RPB;
    for (int r = 0; r < RPB; ++r) at[r][tid] = ab[(row0 + r) * CC + tid];
    __syncthreads();

    float acc[RPB];
    #pragma unroll
    for (int r = 0; r < RPB; ++r) acc[r] = 0.f;

    for (int c0 = 0; c0 < CC; c0 += 4) {
        float w0 = Wo[(long)(c0 + 0) * CC + tid];
        float w1 = Wo[(long)(c0 + 1) * CC + tid];
        float w2 = Wo[(long)(c0 + 2) * CC + tid];
        float w3 = Wo[(long)(c0 + 3) * CC + tid];
        #pragma unroll
        for (int r = 0; r < RPB; ++r) {
            const float4 h4 = *(const float4*)&at[r][c0];
            acc[r] = fmaf(h4.x, w0, fmaf(h4.y, w1, fmaf(h4.z, w2, fmaf(h4.w, w3, acc[r]))));
        }
    }
    const float bb = bo[tid];
    #pragma unroll
    for (int r = 0; r < RPB; ++r) {
        const long i = (row0 + r) * CC + tid;
        out[i] = x[i] + acc[r] + bb;
    }
}

// ---------------- K4: LN2 + FFN + residual (in place on d_out) ----------------
// grid = (B*T)/RPB, block = 384. Hidden row kept in LDS; no global ff buffer.
__global__ __launch_bounds__(CC) void ffn_kernel(
        const float* __restrict__ W1, const float* __restrict__ b1,
        const float* __restrict__ W2, const float* __restrict__ b2,
        const float* __restrict__ g2, const float* __restrict__ be2,
        float* xo) {
    __shared__ float hn[RPB][CC];
    __shared__ float h1[RPB][DFF];
    __shared__ float red[16];
    const int tid = threadIdx.x;
    const long row0 = (long)blockIdx.x * RPB;

    for (int r = 0; r < RPB; ++r) {
        float v = xo[(row0 + r) * CC + tid];
        float s = v, sq = v * v;
        block_reduce2(s, sq, red);
        float mu  = s  * (1.0f / CC);
        float var = sq * (1.0f / CC) - mu * mu;
        float rs  = rsqrtf(var + EPSV);
        hn[r][tid] = (v - mu) * rs * g2[tid] + be2[tid];
        __syncthreads();
    }

    float a1[4][RPB];
    #pragma unroll
    for (int k = 0; k < 4; ++k)
        #pragma unroll
        for (int r = 0; r < RPB; ++r) a1[k][r] = 0.f;

    for (int c0 = 0; c0 < CC; c0 += 4) {
        float w[4][4];
        #pragma unroll
        for (int i = 0; i < 4; ++i)
            #pragma unroll
            for (int k = 0; k < 4; ++k)
                w[i][k] = W1[(long)(c0 + i) * DFF + k * CC + tid];
        #pragma unroll
        for (int r = 0; r < RPB; ++r) {
            const float4 h4 = *(const float4*)&hn[r][c0];
            #pragma unroll
            for (int k = 0; k < 4; ++k)
                a1[k][r] = fmaf(h4.x, w[0][k], fmaf(h4.y, w[1][k],
                           fmaf(h4.z, w[2][k], fmaf(h4.w, w[3][k], a1[k][r]))));
        }
    }
    #pragma unroll
    for (int k = 0; k < 4; ++k) {
        const float bb = b1[k * CC + tid];
        #pragma unroll
        for (int r = 0; r < RPB; ++r)
            h1[r][k * CC + tid] = fmaxf(a1[k][r] + bb, 0.f);
    }
    __syncthreads();

    float a2[RPB];
    #pragma unroll
    for (int r = 0; r < RPB; ++r) a2[r] = 0.f;

    for (int c0 = 0; c0 < DFF; c0 += 4) {
        float w0 = W2[(long)(c0 + 0) * CC + tid];
        float w1 = W2[(long)(c0 + 1) * CC + tid];
        float w2 = W2[(long)(c0 + 2) * CC + tid];
        float w3 = W2[(long)(c0 + 3) * CC + tid];
        #pragma unroll
        for (int r = 0; r < RPB; ++r) {
            const float4 h4 = *(const float4*)&h1[r][c0];
            a2[r] = fmaf(h4.x, w0, fmaf(h4.y, w1, fmaf(h4.z, w2, fmaf(h4.w, w3, a2[r]))));
        }
    }
    const float bb2 = b2[tid];
    #pragma unroll
    for (int r = 0; r < RPB; ++r) {
        const long i = (row0 + r) * CC + tid;
        xo[i] = xo[i] + a2[r] + bb2;
    }
}

// ---------------- launcher ----------------------------------------------------
extern "C" void kernel_launch(void* const* d_in, const int* in_sizes, int n_in,
                              void* d_out, int out_size, void* d_ws, size_t ws_size,
                              hipStream_t stream) {
    const float* x   = (const float*)d_in[0];
    const float* Wq  = (const float*)d_in[1];
    const float* Wk  = (const float*)d_in[2];
    const float* Wv  = (const float*)d_in[3];
    const float* Wo  = (const float*)d_in[4];
    const float* bo  = (const float*)d_in[5];
    const float* W1  = (const float*)d_in[6];
    const float* b1  = (const float*)d_in[7];
    const float* W2  = (const float*)d_in[8];
    const float* b2  = (const float*)d_in[9];
    const float* g1  = (const float*)d_in[10];
    const float* be1 = (const float*)d_in[11];
    const float* g2  = (const float*)d_in[12];
    const float* be2 = (const float*)d_in[13];

    float* out = (float*)d_out;
    float* ws  = (float*)d_ws;

    const long NTOK = (long)BB * TT;        // 32768
    const long QSZ  = NTOK * CC;            // 12,582,912 floats
    float* qb = ws;
    float* kb = ws + QSZ;
    float* vb = ws + 2 * QSZ;
    float* ab = ws + 3 * QSZ;               // total ws use: 4*QSZ*4B = 201.3 MB

    qkv_kernel <<<(int)(NTOK / RPB), CC, 0, stream>>>(x, Wq, Wk, Wv, g1, be1, qb, kb, vb);
    attn_kernel<<<BB * HH,           TT, 0, stream>>>(qb, kb, vb, ab);
    proj_kernel<<<(int)(NTOK / RPB), CC, 0, stream>>>(ab, x, Wo, bo, out);
    ffn_kernel <<<(int)(NTOK / RPB), CC, 0, stream>>>(W1, b1, W2, b2, g2, be2, out);
}

// Round 2
// 738.324 us; speedup vs baseline: 4.5557x; 4.5557x over previous
//
#include <hip/hip_runtime.h>
#include <hip/hip_bf16.h>

#define BB   128
#define TT   256
#define CC   384
#define HH   6
#define HSZ  64
#define DFF  1536
#define EPSV 1e-5f
#define RPB  8
#define NTOK (BB * TT)          // 32768
#define NQKV (3 * CC)           // 1152

typedef __attribute__((ext_vector_type(8))) short  short8;
typedef __attribute__((ext_vector_type(4))) float  f32x4;
typedef __hip_bfloat16 bf16;

// ---------------- block-wide reduction over 384 threads (6 waves) -------------
__device__ __forceinline__ void block_reduce2(float& a, float& b, float* red) {
    #pragma unroll
    for (int off = 32; off > 0; off >>= 1) {
        a += __shfl_down(a, off, 64);
        b += __shfl_down(b, off, 64);
    }
    const int lane = threadIdx.x & 63;
    const int wid  = threadIdx.x >> 6;
    if (lane == 0) { red[wid * 2] = a; red[wid * 2 + 1] = b; }
    __syncthreads();
    if (threadIdx.x == 0) {
        float sa = 0.f, sb = 0.f;
        #pragma unroll
        for (int w = 0; w < 6; ++w) { sa += red[w * 2]; sb += red[w * 2 + 1]; }
        red[12] = sa; red[13] = sb;
    }
    __syncthreads();
    a = red[12]; b = red[13];
}

// ---------------- LN -> bf16 --------------------------------------------------
// grid = NTOK/RPB, block = 384
__global__ __launch_bounds__(CC) void ln_bf16_kernel(
        const float* __restrict__ x, const float* __restrict__ g,
        const float* __restrict__ be, bf16* __restrict__ y) {
    __shared__ float red[16];
    const int tid = threadIdx.x;
    const long row0 = (long)blockIdx.x * RPB;
    const float gg = g[tid], bb = be[tid];
    for (int r = 0; r < RPB; ++r) {
        float v = x[(row0 + r) * CC + tid];
        float s = v, sq = v * v;
        block_reduce2(s, sq, red);
        float mu  = s  * (1.0f / CC);
        float var = sq * (1.0f / CC) - mu * mu;
        float rs  = rsqrtf(var + EPSV);
        y[(row0 + r) * CC + tid] = __float2bfloat16((v - mu) * rs * gg + bb);
        __syncthreads();
    }
}

// ---------------- weight packing ----------------------------------------------
// WcatT[n][k], n in [0,1152): n<384 -> Wq head n/64 dim n%64; then Wk; then Wv.
__global__ __launch_bounds__(CC) void pack_qkv_w(
        const float* __restrict__ Wq, const float* __restrict__ Wk,
        const float* __restrict__ Wv, bf16* __restrict__ WcatT) {
    const int n = blockIdx.x, k = threadIdx.x;
    const float* src; int nn;
    if (n < CC)          { src = Wq; nn = n; }
    else if (n < 2 * CC) { src = Wk; nn = n - CC; }
    else                 { src = Wv; nn = n - 2 * CC; }
    const int h = nn >> 6, d = nn & 63;
    WcatT[(long)n * CC + k] = __float2bfloat16(src[((long)h * CC + k) * HSZ + d]);
}

// in fp32 [R][Cn] -> out bf16 [Cn][R];  R,Cn multiples of 32. block=256, grid=(Cn/32,R/32)
__global__ __launch_bounds__(256) void transpose_to_bf16(
        const float* __restrict__ in, bf16* __restrict__ out, int R, int Cn) {
    __shared__ float t[32][33];
    const int tid = threadIdx.x;
    const int tx = tid & 31, ty = tid >> 5;
    const int c0 = blockIdx.x * 32, r0 = blockIdx.y * 32;
    #pragma unroll
    for (int p = 0; p < 4; ++p)
        t[ty + p * 8][tx] = in[(long)(r0 + ty + p * 8) * Cn + c0 + tx];
    __syncthreads();
    #pragma unroll
    for (int p = 0; p < 4; ++p)
        out[(long)(c0 + ty + p * 8) * R + r0 + tx] = __float2bfloat16(t[tx][ty + p * 8]);
}

// ---------------- MFMA GEMM: C[M,N] = A[M,K] * BT[N,K]^T  ---------------------
// 128x128 block tile, BK=64, 4 waves each computing 64x64 (4x4 of 16x16x32).
// EPI: 0 = plain fp32 store; 1 = bias+relu -> bf16; 2 = bias+residual -> fp32
template<int K, int EPI>
__global__ __launch_bounds__(256) void gemm_bt(
        const bf16* __restrict__ A, const bf16* __restrict__ BT,
        const float* __restrict__ bias, const float* __restrict__ res,
        float* __restrict__ outF, bf16* __restrict__ outB, int N) {
    __shared__ bf16 As[128][72];
    __shared__ bf16 Bs[128][72];

    const int tid = threadIdx.x;
    const int m0 = blockIdx.x * 128;
    const int n0 = blockIdx.y * 128;

    const int ln   = tid & 63;
    const int wid  = tid >> 6;
    const int wm   = (wid & 1) * 64;
    const int wn   = (wid >> 1) * 64;
    const int fr   = ln & 15;
    const int quad = ln >> 4;

    const int srow = tid >> 3;          // 0..31
    const int sc   = (tid & 7) * 8;     // 0..56, 16B chunks

    f32x4 acc[4][4];
    #pragma unroll
    for (int i = 0; i < 4; ++i)
        #pragma unroll
        for (int j = 0; j < 4; ++j)
            acc[i][j] = (f32x4){0.f, 0.f, 0.f, 0.f};

    for (int k0 = 0; k0 < K; k0 += 64) {
        __syncthreads();
        #pragma unroll
        for (int p = 0; p < 4; ++p) {
            const int r = p * 32 + srow;
            *(uint4*)&As[r][sc] = *(const uint4*)&A [(long)(m0 + r) * K + k0 + sc];
            *(uint4*)&Bs[r][sc] = *(const uint4*)&BT[(long)(n0 + r) * K + k0 + sc];
        }
        __syncthreads();
        #pragma unroll
        for (int kk = 0; kk < 64; kk += 32) {
            short8 af[4], bfr[4];
            #pragma unroll
            for (int i = 0; i < 4; ++i)
                af[i] = *(const short8*)&As[wm + i * 16 + fr][kk + quad * 8];
            #pragma unroll
            for (int j = 0; j < 4; ++j)
                bfr[j] = *(const short8*)&Bs[wn + j * 16 + fr][kk + quad * 8];
            #pragma unroll
            for (int i = 0; i < 4; ++i)
                #pragma unroll
                for (int j = 0; j < 4; ++j)
                    acc[i][j] = __builtin_amdgcn_mfma_f32_16x16x32_bf16(
                        af[i], bfr[j], acc[i][j], 0, 0, 0);
        }
    }

    // epilogue: D[row=quad*4+r][col=lane&15]
    #pragma unroll
    for (int i = 0; i < 4; ++i) {
        #pragma unroll
        for (int j = 0; j < 4; ++j) {
            const int col = n0 + wn + j * 16 + fr;
            #pragma unroll
            for (int r = 0; r < 4; ++r) {
                const int row = m0 + wm + i * 16 + quad * 4 + r;
                const long idx = (long)row * N + col;
                float v = acc[i][j][r];
                if (EPI == 0) {
                    outF[idx] = v;
                } else if (EPI == 1) {
                    v = fmaxf(v + bias[col], 0.f);
                    outB[idx] = __float2bfloat16(v);
                } else {
                    outF[idx] = v + bias[col] + res[idx];
                }
            }
        }
    }
}

// ---------------- causal flash attention (fp32 VALU) --------------------------
// grid = B*H, block = 256; thread t owns query row t. q/k/v live in qkv[M][1152].
struct alignas(8) bh4 { bf16 x, y, z, w; };
__global__ __launch_bounds__(TT) void attn_kernel(
        const float* __restrict__ qkv, bf16* __restrict__ ab) {
    __shared__ float Kt[64][64];
    __shared__ float Vt[64][64];
    const int t  = threadIdx.x;
    const int bh = blockIdx.x;
    const int b = bh / HH, h = bh % HH;

    const float4* qp = (const float4*)(qkv + ((long)(b * TT) + t) * NQKV + h * HSZ);
    float4 qv[16], ov[16];
    #pragma unroll
    for (int i = 0; i < 16; ++i) { qv[i] = qp[i]; ov[i] = make_float4(0.f, 0.f, 0.f, 0.f); }

    float m = -1e30f, l = 0.f;

    for (int s0 = 0; s0 < TT; s0 += 64) {
        __syncthreads();
        {
            const float* kbase = qkv + (long)(b * TT + s0) * NQKV + CC + h * HSZ;
            const float* vbase = kbase + CC;
            for (int i = t; i < 64 * 16; i += TT) {
                const int row = i >> 4, c = i & 15;
                ((float4*)&Kt[row][0])[c] = *(const float4*)&kbase[(long)row * NQKV + c * 4];
                ((float4*)&Vt[row][0])[c] = *(const float4*)&vbase[(long)row * NQKV + c * 4];
            }
        }
        __syncthreads();

        int ns = t - s0 + 1;
        if (ns > 64) ns = 64;
        for (int si = 0; si < ns; ++si) {
            const float4* krow = (const float4*)&Kt[si][0];
            float d0 = 0.f, d1 = 0.f, d2 = 0.f, d3 = 0.f;
            #pragma unroll
            for (int i = 0; i < 16; ++i) {
                float4 kk = krow[i];
                d0 = fmaf(qv[i].x, kk.x, d0);
                d1 = fmaf(qv[i].y, kk.y, d1);
                d2 = fmaf(qv[i].z, kk.z, d2);
                d3 = fmaf(qv[i].w, kk.w, d3);
            }
            const float sc = (d0 + d1 + d2 + d3) * 0.125f;
            if (sc > m) {
                const float alpha = __expf(m - sc);
                l *= alpha;
                #pragma unroll
                for (int i = 0; i < 16; ++i) {
                    ov[i].x *= alpha; ov[i].y *= alpha;
                    ov[i].z *= alpha; ov[i].w *= alpha;
                }
                m = sc;
            }
            const float p = __expf(sc - m);
            l += p;
            const float4* vrow = (const float4*)&Vt[si][0];
            #pragma unroll
            for (int i = 0; i < 16; ++i) {
                float4 vv = vrow[i];
                ov[i].x = fmaf(p, vv.x, ov[i].x);
                ov[i].y = fmaf(p, vv.y, ov[i].y);
                ov[i].z = fmaf(p, vv.z, ov[i].z);
                ov[i].w = fmaf(p, vv.w, ov[i].w);
            }
        }
    }

    const float inv = 1.0f / l;
    bh4* op = (bh4*)(ab + ((long)(b * TT) + t) * CC + h * HSZ);
    #pragma unroll
    for (int i = 0; i < 16; ++i) {
        bh4 o;
        o.x = __float2bfloat16(ov[i].x * inv);
        o.y = __float2bfloat16(ov[i].y * inv);
        o.z = __float2bfloat16(ov[i].z * inv);
        o.w = __float2bfloat16(ov[i].w * inv);
        op[i] = o;
    }
}

// ---------------- launcher ----------------------------------------------------
extern "C" void kernel_launch(void* const* d_in, const int* in_sizes, int n_in,
                              void* d_out, int out_size, void* d_ws, size_t ws_size,
                              hipStream_t stream) {
    const float* x   = (const float*)d_in[0];
    const float* Wq  = (const float*)d_in[1];
    const float* Wk  = (const float*)d_in[2];
    const float* Wv  = (const float*)d_in[3];
    const float* Wo  = (const float*)d_in[4];
    const float* bo  = (const float*)d_in[5];
    const float* W1  = (const float*)d_in[6];
    const float* b1  = (const float*)d_in[7];
    const float* W2  = (const float*)d_in[8];
    const float* b2  = (const float*)d_in[9];
    const float* g1  = (const float*)d_in[10];
    const float* be1 = (const float*)d_in[11];
    const float* g2  = (const float*)d_in[12];
    const float* be2 = (const float*)d_in[13];

    float* out = (float*)d_out;
    char*  ws  = (char*)d_ws;

    // workspace layout (all 256B aligned):
    //   [0)                : qkv fp32 [NTOK][1152]  (151.0 MB)  -- reused as ff1 bf16 [NTOK][1536] (100.7 MB)
    //   [actOff)           : act bf16 [NTOK][384]   (25.2 MB)   -- h1n, then attn, then h2n (disjoint lifetimes)
    //   [wOff)             : WcatT / WoT / W1T / W2T bf16
    const size_t qkvBytes = (size_t)NTOK * NQKV * 4;          // 150,994,944
    const size_t actOff   = (qkvBytes + 255) & ~(size_t)255;
    const size_t actBytes = (size_t)NTOK * CC * 2;            // 25,165,824
    size_t wOff = (actOff + actBytes + 255) & ~(size_t)255;

    float* qkvb = (float*)ws;
    bf16*  ff1  = (bf16*)ws;                  // after attention is done with qkvb
    bf16*  actb = (bf16*)(ws + actOff);       // h1n / attn-out / h2n

    bf16* WcatT = (bf16*)(ws + wOff); wOff += (size_t)NQKV * CC * 2 + 256;
    bf16* WoT   = (bf16*)(ws + ((wOff + 255) & ~(size_t)255)); wOff = ((wOff + 255) & ~(size_t)255) + (size_t)CC * CC * 2;
    bf16* W1T   = (bf16*)(ws + ((wOff + 255) & ~(size_t)255)); wOff = ((wOff + 255) & ~(size_t)255) + (size_t)DFF * CC * 2;
    bf16* W2T   = (bf16*)(ws + ((wOff + 255) & ~(size_t)255));

    // --- weight conversion (bf16, transposed) ---
    pack_qkv_w      <<<NQKV, CC, 0, stream>>>(Wq, Wk, Wv, WcatT);
    transpose_to_bf16<<<dim3(CC / 32,  CC / 32),  256, 0, stream>>>(Wo, WoT, CC,  CC);
    transpose_to_bf16<<<dim3(DFF / 32, CC / 32),  256, 0, stream>>>(W1, W1T, CC,  DFF);
    transpose_to_bf16<<<dim3(CC / 32,  DFF / 32), 256, 0, stream>>>(W2, W2T, DFF, CC);

    // --- attention half ---
    ln_bf16_kernel<<<NTOK / RPB, CC, 0, stream>>>(x, g1, be1, actb);               // h1n
    gemm_bt<CC, 0><<<dim3(NTOK / 128, NQKV / 128), 256, 0, stream>>>(
        actb, WcatT, nullptr, nullptr, qkvb, nullptr, NQKV);                        // q,k,v
    attn_kernel<<<BB * HH, TT, 0, stream>>>(qkvb, actb);                            // attn (bf16)
    gemm_bt<CC, 2><<<dim3(NTOK / 128, CC / 128), 256, 0, stream>>>(
        actb, WoT, bo, x, out, nullptr, CC);                                        // x2 = x + attn@Wo + bo

    // --- FFN half ---
    ln_bf16_kernel<<<NTOK / RPB, CC, 0, stream>>>(out, g2, be2, actb);              // h2n
    gemm_bt<CC, 1><<<dim3(NTOK / 128, DFF / 128), 256, 0, stream>>>(
        actb, W1T, b1, nullptr, nullptr, ff1, DFF);                                 // ff1 = relu(h2@W1+b1)
    gemm_bt<DFF, 2><<<dim3(NTOK / 128, CC / 128), 256, 0, stream>>>(
        ff1, W2T, b2, out, out, nullptr, CC);                                       // out = x2 + ff1@W2 + b2
}

// Round 3
// 561.119 us; speedup vs baseline: 5.9945x; 1.3158x over previous
//
#include <hip/hip_runtime.h>
#include <hip/hip_bf16.h>

#define BB   128
#define TT   256
#define CC   384
#define HH   6
#define HSZ  64
#define DFF  1536
#define EPSV 1e-5f
#define RPB  8
#define NTOK (BB * TT)          // 32768
#define NQKV (3 * CC)           // 1152

typedef __attribute__((ext_vector_type(8))) short  short8;
typedef __attribute__((ext_vector_type(4))) float  f32x4;
typedef __hip_bfloat16 bf16;

// ---------------- block-wide reduction over 384 threads (6 waves) -------------
__device__ __forceinline__ void block_reduce2(float& a, float& b, float* red) {
    #pragma unroll
    for (int off = 32; off > 0; off >>= 1) {
        a += __shfl_down(a, off, 64);
        b += __shfl_down(b, off, 64);
    }
    const int lane = threadIdx.x & 63;
    const int wid  = threadIdx.x >> 6;
    if (lane == 0) { red[wid * 2] = a; red[wid * 2 + 1] = b; }
    __syncthreads();
    if (threadIdx.x == 0) {
        float sa = 0.f, sb = 0.f;
        #pragma unroll
        for (int w = 0; w < 6; ++w) { sa += red[w * 2]; sb += red[w * 2 + 1]; }
        red[12] = sa; red[13] = sb;
    }
    __syncthreads();
    a = red[12]; b = red[13];
}

// ---------------- LN -> bf16 --------------------------------------------------
__global__ __launch_bounds__(CC) void ln_bf16_kernel(
        const float* __restrict__ x, const float* __restrict__ g,
        const float* __restrict__ be, bf16* __restrict__ y) {
    __shared__ float red[16];
    const int tid = threadIdx.x;
    const long row0 = (long)blockIdx.x * RPB;
    const float gg = g[tid], bb = be[tid];
    for (int r = 0; r < RPB; ++r) {
        float v = x[(row0 + r) * CC + tid];
        float s = v, sq = v * v;
        block_reduce2(s, sq, red);
        float mu  = s  * (1.0f / CC);
        float var = sq * (1.0f / CC) - mu * mu;
        float rs  = rsqrtf(var + EPSV);
        y[(row0 + r) * CC + tid] = __float2bfloat16((v - mu) * rs * gg + bb);
        __syncthreads();
    }
}

// ---------------- weight packing ----------------------------------------------
__global__ __launch_bounds__(CC) void pack_qkv_w(
        const float* __restrict__ Wq, const float* __restrict__ Wk,
        const float* __restrict__ Wv, bf16* __restrict__ WcatT) {
    const int n = blockIdx.x, k = threadIdx.x;
    const float* src; int nn;
    if (n < CC)          { src = Wq; nn = n; }
    else if (n < 2 * CC) { src = Wk; nn = n - CC; }
    else                 { src = Wv; nn = n - 2 * CC; }
    const int h = nn >> 6, d = nn & 63;
    WcatT[(long)n * CC + k] = __float2bfloat16(src[((long)h * CC + k) * HSZ + d]);
}

__global__ __launch_bounds__(256) void transpose_to_bf16(
        const float* __restrict__ in, bf16* __restrict__ out, int R, int Cn) {
    __shared__ float t[32][33];
    const int tid = threadIdx.x;
    const int tx = tid & 31, ty = tid >> 5;
    const int c0 = blockIdx.x * 32, r0 = blockIdx.y * 32;
    #pragma unroll
    for (int p = 0; p < 4; ++p)
        t[ty + p * 8][tx] = in[(long)(r0 + ty + p * 8) * Cn + c0 + tx];
    __syncthreads();
    #pragma unroll
    for (int p = 0; p < 4; ++p)
        out[(long)(c0 + ty + p * 8) * R + r0 + tx] = __float2bfloat16(t[tx][ty + p * 8]);
}

// ---------------- MFMA GEMM: C[M,N] = A[M,K] * BT[N,K]^T  ---------------------
// EPI: 0 = fp32 store; 1 = bias+relu -> bf16; 2 = bias+residual -> fp32; 3 = bf16 store
template<int K, int EPI>
__global__ __launch_bounds__(256) void gemm_bt(
        const bf16* __restrict__ A, const bf16* __restrict__ BT,
        const float* __restrict__ bias, const float* __restrict__ res,
        float* __restrict__ outF, bf16* __restrict__ outB, int N) {
    __shared__ bf16 As[128][72];
    __shared__ bf16 Bs[128][72];

    const int tid = threadIdx.x;
    const int m0 = blockIdx.x * 128;
    const int n0 = blockIdx.y * 128;

    const int ln   = tid & 63;
    const int wid  = tid >> 6;
    const int wm   = (wid & 1) * 64;
    const int wn   = (wid >> 1) * 64;
    const int fr   = ln & 15;
    const int quad = ln >> 4;

    const int srow = tid >> 3;
    const int sc   = (tid & 7) * 8;

    f32x4 acc[4][4];
    #pragma unroll
    for (int i = 0; i < 4; ++i)
        #pragma unroll
        for (int j = 0; j < 4; ++j)
            acc[i][j] = (f32x4){0.f, 0.f, 0.f, 0.f};

    for (int k0 = 0; k0 < K; k0 += 64) {
        __syncthreads();
        #pragma unroll
        for (int p = 0; p < 4; ++p) {
            const int r = p * 32 + srow;
            *(uint4*)&As[r][sc] = *(const uint4*)&A [(long)(m0 + r) * K + k0 + sc];
            *(uint4*)&Bs[r][sc] = *(const uint4*)&BT[(long)(n0 + r) * K + k0 + sc];
        }
        __syncthreads();
        #pragma unroll
        for (int kk = 0; kk < 64; kk += 32) {
            short8 af[4], bfr[4];
            #pragma unroll
            for (int i = 0; i < 4; ++i)
                af[i] = *(const short8*)&As[wm + i * 16 + fr][kk + quad * 8];
            #pragma unroll
            for (int j = 0; j < 4; ++j)
                bfr[j] = *(const short8*)&Bs[wn + j * 16 + fr][kk + quad * 8];
            #pragma unroll
            for (int i = 0; i < 4; ++i)
                #pragma unroll
                for (int j = 0; j < 4; ++j)
                    acc[i][j] = __builtin_amdgcn_mfma_f32_16x16x32_bf16(
                        af[i], bfr[j], acc[i][j], 0, 0, 0);
        }
    }

    #pragma unroll
    for (int i = 0; i < 4; ++i) {
        #pragma unroll
        for (int j = 0; j < 4; ++j) {
            const int col = n0 + wn + j * 16 + fr;
            #pragma unroll
            for (int r = 0; r < 4; ++r) {
                const int row = m0 + wm + i * 16 + quad * 4 + r;
                const long idx = (long)row * N + col;
                float v = acc[i][j][r];
                if (EPI == 0) {
                    outF[idx] = v;
                } else if (EPI == 1) {
                    v = fmaxf(v + bias[col], 0.f);
                    outB[idx] = __float2bfloat16(v);
                } else if (EPI == 2) {
                    outF[idx] = v + bias[col] + res[idx];
                } else {
                    outB[idx] = __float2bfloat16(v);
                }
            }
        }
    }
}

// ---------------- MFMA causal flash attention ---------------------------------
// grid = B*H, block = 256 (4 waves). Wave w owns q-row tiles rb = w*16 + 64*i
// (i=0..3) -> every wave does exactly 10 (i,s)-units. qkv is bf16 [tok][1152].
struct alignas(8) bh4s { bf16 a, b, c, d; };

__global__ __launch_bounds__(256, 2) void attn_mfma_kernel(
        const bf16* __restrict__ qkv, bf16* __restrict__ ab) {
    __shared__ bf16 Kt[64][72];        // [s][d]
    __shared__ bf16 Vt[64][72];        // [d][s] transposed
    __shared__ bf16 Pb[4][16][72];     // per-wave P / O staging

    const int tid  = threadIdx.x;
    const int bh   = blockIdx.x;
    const int b    = bh / HH, h = bh % HH;
    const int w    = tid >> 6;
    const int ln   = tid & 63;
    const int ln15 = ln & 15;
    const int quad = ln >> 4;

    // Q fragments (A-layout): lane holds Q[rb+ln15][quad*8+j (+32)]
    short8 qf[4][2];
    #pragma unroll
    for (int i = 0; i < 4; ++i) {
        const long tok = (long)b * TT + w * 16 + i * 64 + ln15;
        const bf16* p = qkv + tok * NQKV + h * HSZ + quad * 8;
        qf[i][0] = *(const short8*)p;
        qf[i][1] = *(const short8*)(p + 32);
    }

    f32x4 accO[4][4];
    float mrow[4][4], lrow[4][4];
    #pragma unroll
    for (int i = 0; i < 4; ++i) {
        #pragma unroll
        for (int j = 0; j < 4; ++j) accO[i][j] = (f32x4){0.f, 0.f, 0.f, 0.f};
        #pragma unroll
        for (int r = 0; r < 4; ++r) { mrow[i][r] = -1e30f; lrow[i][r] = 0.f; }
    }

    for (int sidx = 0; sidx < 4; ++sidx) {
        const int s0 = sidx * 64;
        __syncthreads();
        {   // stage K (coalesced 16B)
            const bf16* kg = qkv + (long)(b * TT + s0) * NQKV + CC + h * HSZ;
            #pragma unroll
            for (int it = 0; it < 2; ++it) {
                const int u = tid + it * 256;
                const int r = u >> 3, c = (u & 7) * 8;
                *(uint4*)&Kt[r][c] = *(const uint4*)(kg + (long)r * NQKV + c);
            }
            // stage V transposed: lane s=tid&63 -> consecutive LDS dwords (2-way max)
            const bf16* vg = qkv + (long)(b * TT + s0) * NQKV + 2 * CC + h * HSZ;
            const int s = tid & 63;
            #pragma unroll
            for (int it = 0; it < 4; ++it) {
                const int dq = (tid >> 6) + it * 4;      // 0..15
                const bh4s vv = *(const bh4s*)(vg + (long)s * NQKV + dq * 4);
                Vt[dq * 4 + 0][s] = vv.a;
                Vt[dq * 4 + 1][s] = vv.b;
                Vt[dq * 4 + 2][s] = vv.c;
                Vt[dq * 4 + 3][s] = vv.d;
            }
        }
        __syncthreads();

        for (int i = sidx; i < 4; ++i) {          // uniform across waves
            const int rb = w * 16 + i * 64;
            // S = Q_i @ K^T
            f32x4 S[4];
            #pragma unroll
            for (int jt = 0; jt < 4; ++jt) S[jt] = (f32x4){0.f, 0.f, 0.f, 0.f};
            #pragma unroll
            for (int ks = 0; ks < 2; ++ks) {
                #pragma unroll
                for (int jt = 0; jt < 4; ++jt) {
                    const short8 kf = *(const short8*)&Kt[jt * 16 + ln15][ks * 32 + quad * 8];
                    S[jt] = __builtin_amdgcn_mfma_f32_16x16x32_bf16(qf[i][ks], kf, S[jt], 0, 0, 0);
                }
            }
            // scale + causal mask + row max
            float rmax[4];
            #pragma unroll
            for (int r = 0; r < 4; ++r) rmax[r] = -1e30f;
            #pragma unroll
            for (int jt = 0; jt < 4; ++jt) {
                #pragma unroll
                for (int r = 0; r < 4; ++r) {
                    float v = S[jt][r] * 0.125f;
                    if (i == sidx) {
                        const int col = s0 + jt * 16 + ln15;
                        const int row = rb + quad * 4 + r;
                        if (col > row) v = -1e30f;
                    }
                    S[jt][r] = v;
                    rmax[r] = fmaxf(rmax[r], v);
                }
            }
            #pragma unroll
            for (int off = 1; off < 16; off <<= 1)
                #pragma unroll
                for (int r = 0; r < 4; ++r)
                    rmax[r] = fmaxf(rmax[r], __shfl_xor(rmax[r], off, 64));

            float alpha[4], rsum[4];
            #pragma unroll
            for (int r = 0; r < 4; ++r) {
                const float mn = fmaxf(mrow[i][r], rmax[r]);
                alpha[r] = __expf(mrow[i][r] - mn);
                mrow[i][r] = mn;
                rsum[r] = 0.f;
            }
            #pragma unroll
            for (int jt = 0; jt < 4; ++jt)
                #pragma unroll
                for (int r = 0; r < 4; ++r) {
                    const float p = __expf(S[jt][r] - mrow[i][r]);
                    S[jt][r] = p;
                    rsum[r] += p;
                }
            #pragma unroll
            for (int off = 1; off < 16; off <<= 1)
                #pragma unroll
                for (int r = 0; r < 4; ++r)
                    rsum[r] += __shfl_xor(rsum[r], off, 64);
            #pragma unroll
            for (int r = 0; r < 4; ++r)
                lrow[i][r] = lrow[i][r] * alpha[r] + rsum[r];
            #pragma unroll
            for (int jt = 0; jt < 4; ++jt)
                #pragma unroll
                for (int r = 0; r < 4; ++r)
                    accO[i][jt][r] *= alpha[r];

            // P: C-layout -> LDS -> A-layout (per-wave buffer, same-wave RAW only)
            #pragma unroll
            for (int jt = 0; jt < 4; ++jt)
                #pragma unroll
                for (int r = 0; r < 4; ++r)
                    Pb[w][quad * 4 + r][jt * 16 + ln15] = __float2bfloat16(S[jt][r]);
            const short8 pf0 = *(const short8*)&Pb[w][ln15][quad * 8];
            const short8 pf1 = *(const short8*)&Pb[w][ln15][32 + quad * 8];
            // O += P @ V
            #pragma unroll
            for (int jt = 0; jt < 4; ++jt) {
                const short8 vf0 = *(const short8*)&Vt[jt * 16 + ln15][quad * 8];
                const short8 vf1 = *(const short8*)&Vt[jt * 16 + ln15][32 + quad * 8];
                accO[i][jt] = __builtin_amdgcn_mfma_f32_16x16x32_bf16(pf0, vf0, accO[i][jt], 0, 0, 0);
                accO[i][jt] = __builtin_amdgcn_mfma_f32_16x16x32_bf16(pf1, vf1, accO[i][jt], 0, 0, 0);
            }
        }
    }

    // epilogue: normalize, stage through per-wave LDS, coalesced bf16 store
    #pragma unroll
    for (int i = 0; i < 4; ++i) {
        const int rb = w * 16 + i * 64;
        float inv[4];
        #pragma unroll
        for (int r = 0; r < 4; ++r) inv[r] = 1.0f / lrow[i][r];
        #pragma unroll
        for (int jt = 0; jt < 4; ++jt)
            #pragma unroll
            for (int r = 0; r < 4; ++r)
                Pb[w][quad * 4 + r][jt * 16 + ln15] = __float2bfloat16(accO[i][jt][r] * inv[r]);
        #pragma unroll
        for (int it = 0; it < 2; ++it) {
            const int u = ln + it * 64;
            const int row = u >> 3, ch = (u & 7) * 8;
            const long tok = (long)b * TT + rb + row;
            *(uint4*)(ab + tok * CC + h * HSZ + ch) = *(const uint4*)&Pb[w][row][ch];
        }
    }
}

// ---------------- launcher ----------------------------------------------------
extern "C" void kernel_launch(void* const* d_in, const int* in_sizes, int n_in,
                              void* d_out, int out_size, void* d_ws, size_t ws_size,
                              hipStream_t stream) {
    const float* x   = (const float*)d_in[0];
    const float* Wq  = (const float*)d_in[1];
    const float* Wk  = (const float*)d_in[2];
    const float* Wv  = (const float*)d_in[3];
    const float* Wo  = (const float*)d_in[4];
    const float* bo  = (const float*)d_in[5];
    const float* W1  = (const float*)d_in[6];
    const float* b1  = (const float*)d_in[7];
    const float* W2  = (const float*)d_in[8];
    const float* b2  = (const float*)d_in[9];
    const float* g1  = (const float*)d_in[10];
    const float* be1 = (const float*)d_in[11];
    const float* g2  = (const float*)d_in[12];
    const float* be2 = (const float*)d_in[13];

    float* out = (float*)d_out;
    char*  ws  = (char*)d_ws;

    // layout: [0) qkv bf16 [NTOK][1152] (75.5MB), reused as ff1 bf16 [NTOK][1536]
    //         [actOff) act bf16 [NTOK][384] ; then packed weights
    const size_t qkvBytes = (size_t)NTOK * NQKV * 4;   // keep prior (safe) offsets
    const size_t actOff   = (qkvBytes + 255) & ~(size_t)255;
    const size_t actBytes = (size_t)NTOK * CC * 2;
    size_t wOff = (actOff + actBytes + 255) & ~(size_t)255;

    bf16* qkvb = (bf16*)ws;
    bf16* ff1  = (bf16*)ws;
    bf16* actb = (bf16*)(ws + actOff);

    bf16* WcatT = (bf16*)(ws + wOff); wOff += (size_t)NQKV * CC * 2 + 256;
    bf16* WoT   = (bf16*)(ws + ((wOff + 255) & ~(size_t)255)); wOff = ((wOff + 255) & ~(size_t)255) + (size_t)CC * CC * 2;
    bf16* W1T   = (bf16*)(ws + ((wOff + 255) & ~(size_t)255)); wOff = ((wOff + 255) & ~(size_t)255) + (size_t)DFF * CC * 2;
    bf16* W2T   = (bf16*)(ws + ((wOff + 255) & ~(size_t)255));

    pack_qkv_w      <<<NQKV, CC, 0, stream>>>(Wq, Wk, Wv, WcatT);
    transpose_to_bf16<<<dim3(CC / 32,  CC / 32),  256, 0, stream>>>(Wo, WoT, CC,  CC);
    transpose_to_bf16<<<dim3(DFF / 32, CC / 32),  256, 0, stream>>>(W1, W1T, CC,  DFF);
    transpose_to_bf16<<<dim3(CC / 32,  DFF / 32), 256, 0, stream>>>(W2, W2T, DFF, CC);

    ln_bf16_kernel<<<NTOK / RPB, CC, 0, stream>>>(x, g1, be1, actb);
    gemm_bt<CC, 3><<<dim3(NTOK / 128, NQKV / 128), 256, 0, stream>>>(
        actb, WcatT, nullptr, nullptr, nullptr, qkvb, NQKV);                // qkv bf16
    attn_mfma_kernel<<<BB * HH, 256, 0, stream>>>(qkvb, actb);              // attn bf16
    gemm_bt<CC, 2><<<dim3(NTOK / 128, CC / 128), 256, 0, stream>>>(
        actb, WoT, bo, x, out, nullptr, CC);                                // x2

    ln_bf16_kernel<<<NTOK / RPB, CC, 0, stream>>>(out, g2, be2, actb);
    gemm_bt<CC, 1><<<dim3(NTOK / 128, DFF / 128), 256, 0, stream>>>(
        actb, W1T, b1, nullptr, nullptr, ff1, DFF);                         // ff1
    gemm_bt<DFF, 2><<<dim3(NTOK / 128, CC / 128), 256, 0, stream>>>(
        ff1, W2T, b2, out, out, nullptr, CC);                               // out
}

// Round 4
// 527.696 us; speedup vs baseline: 6.3741x; 1.0633x over previous
//
#include <hip/hip_runtime.h>
#include <hip/hip_bf16.h>

#define BB   128
#define TT   256
#define CC   384
#define HH   6
#define HSZ  64
#define DFF  1536
#define EPSV 1e-5f
#define RPB  8
#define NTOK (BB * TT)          // 32768
#define NQKV (3 * CC)           // 1152

typedef __attribute__((ext_vector_type(8))) short  short8;
typedef __attribute__((ext_vector_type(4))) float  f32x4;
typedef __hip_bfloat16 bf16;

// async 16B global -> LDS (lane-contiguous at wave-uniform base)
__device__ __forceinline__ void async_copy16(const bf16* g, bf16* l) {
    __builtin_amdgcn_global_load_lds(
        (const __attribute__((address_space(1))) void*)g,
        (__attribute__((address_space(3))) void*)l, 16, 0, 0);
}

// ---------------- block-wide reduction over 384 threads (6 waves) -------------
__device__ __forceinline__ void block_reduce2(float& a, float& b, float* red) {
    #pragma unroll
    for (int off = 32; off > 0; off >>= 1) {
        a += __shfl_down(a, off, 64);
        b += __shfl_down(b, off, 64);
    }
    const int lane = threadIdx.x & 63;
    const int wid  = threadIdx.x >> 6;
    if (lane == 0) { red[wid * 2] = a; red[wid * 2 + 1] = b; }
    __syncthreads();
    if (threadIdx.x == 0) {
        float sa = 0.f, sb = 0.f;
        #pragma unroll
        for (int w = 0; w < 6; ++w) { sa += red[w * 2]; sb += red[w * 2 + 1]; }
        red[12] = sa; red[13] = sb;
    }
    __syncthreads();
    a = red[12]; b = red[13];
}

// ---------------- LN -> bf16 --------------------------------------------------
__global__ __launch_bounds__(CC) void ln_bf16_kernel(
        const float* __restrict__ x, const float* __restrict__ g,
        const float* __restrict__ be, bf16* __restrict__ y) {
    __shared__ float red[16];
    const int tid = threadIdx.x;
    const long row0 = (long)blockIdx.x * RPB;
    const float gg = g[tid], bb = be[tid];
    for (int r = 0; r < RPB; ++r) {
        float v = x[(row0 + r) * CC + tid];
        float s = v, sq = v * v;
        block_reduce2(s, sq, red);
        float mu  = s  * (1.0f / CC);
        float var = sq * (1.0f / CC) - mu * mu;
        float rs  = rsqrtf(var + EPSV);
        y[(row0 + r) * CC + tid] = __float2bfloat16((v - mu) * rs * gg + bb);
        __syncthreads();
    }
}

// ---------------- weight packing ----------------------------------------------
__global__ __launch_bounds__(CC) void pack_qkv_w(
        const float* __restrict__ Wq, const float* __restrict__ Wk,
        const float* __restrict__ Wv, bf16* __restrict__ WcatT) {
    const int n = blockIdx.x, k = threadIdx.x;
    const float* src; int nn;
    if (n < CC)          { src = Wq; nn = n; }
    else if (n < 2 * CC) { src = Wk; nn = n - CC; }
    else                 { src = Wv; nn = n - 2 * CC; }
    const int h = nn >> 6, d = nn & 63;
    WcatT[(long)n * CC + k] = __float2bfloat16(src[((long)h * CC + k) * HSZ + d]);
}

__global__ __launch_bounds__(256) void transpose_to_bf16(
        const float* __restrict__ in, bf16* __restrict__ out, int R, int Cn) {
    __shared__ float t[32][33];
    const int tid = threadIdx.x;
    const int tx = tid & 31, ty = tid >> 5;
    const int c0 = blockIdx.x * 32, r0 = blockIdx.y * 32;
    #pragma unroll
    for (int p = 0; p < 4; ++p)
        t[ty + p * 8][tx] = in[(long)(r0 + ty + p * 8) * Cn + c0 + tx];
    __syncthreads();
    #pragma unroll
    for (int p = 0; p < 4; ++p)
        out[(long)(c0 + ty + p * 8) * R + r0 + tx] = __float2bfloat16(t[tx][ty + p * 8]);
}

// ---------------- MFMA GEMM: C[M,N] = A[M,K] * BT[N,K]^T  ---------------------
// m97 structure: 128x128 tile, BK=64, async global_load_lds staging, XOR-swizzled
// LDS chunks (pos = cc ^ (row&7)) so fragment ds_read_b128 is bank-conflict-free.
// EPI: 0 = fp32 store; 1 = bias+relu -> bf16; 2 = bias+residual -> fp32; 3 = bf16 store
template<int K, int EPI>
__global__ __launch_bounds__(256) void gemm_bt(
        const bf16* __restrict__ A, const bf16* __restrict__ BT,
        const float* __restrict__ bias, const float* __restrict__ res,
        float* __restrict__ outF, bf16* __restrict__ outB, int N) {
    __shared__ bf16 As[128 * 64];
    __shared__ bf16 Bs[128 * 64];

    const int tid = threadIdx.x;
    const int m0 = blockIdx.x * 128;
    const int n0 = blockIdx.y * 128;

    const int ln   = tid & 63;
    const int wid  = tid >> 6;
    const int wm   = (wid & 1) * 64;
    const int wn   = (wid >> 1) * 64;
    const int fr   = ln & 15;
    const int quad = ln >> 4;
    const int sw   = fr & 7;            // row-dependent swizzle key for frag reads

    f32x4 acc[4][4];
    #pragma unroll
    for (int i = 0; i < 4; ++i)
        #pragma unroll
        for (int j = 0; j < 4; ++j)
            acc[i][j] = (f32x4){0.f, 0.f, 0.f, 0.f};

    // per-lane staging geometry (constant across k0)
    const int U    = ((wid * 4) << 6) + ln;     // first chunk id of this wave
    // chunk id u -> row = u>>3, pos = u&7, global col-chunk cc = pos ^ (row&7)

    for (int k0 = 0; k0 < K; k0 += 64) {
        __syncthreads();
        #pragma unroll
        for (int it = 0; it < 4; ++it) {
            const int u   = U + (it << 6);
            const int row = u >> 3;
            const int cc  = (u & 7) ^ (row & 7);
            const long gofs = (long)row * K + k0 + cc * 8;
            async_copy16(A  + (long)m0 * K + gofs, As + u * 8);
            async_copy16(BT + (long)n0 * K + gofs, Bs + u * 8);
        }
        __syncthreads();
        #pragma unroll
        for (int kk = 0; kk < 64; kk += 32) {
            const int cb = (kk >> 3) + quad;    // col-chunk wanted
            short8 af[4], bfr[4];
            #pragma unroll
            for (int i = 0; i < 4; ++i) {
                const int R = wm + i * 16 + fr;
                af[i] = *(const short8*)(As + R * 64 + ((cb ^ sw) << 3));
            }
            #pragma unroll
            for (int j = 0; j < 4; ++j) {
                const int R = wn + j * 16 + fr;
                bfr[j] = *(const short8*)(Bs + R * 64 + ((cb ^ sw) << 3));
            }
            #pragma unroll
            for (int i = 0; i < 4; ++i)
                #pragma unroll
                for (int j = 0; j < 4; ++j)
                    acc[i][j] = __builtin_amdgcn_mfma_f32_16x16x32_bf16(
                        af[i], bfr[j], acc[i][j], 0, 0, 0);
        }
    }

    #pragma unroll
    for (int i = 0; i < 4; ++i) {
        #pragma unroll
        for (int j = 0; j < 4; ++j) {
            const int col = n0 + wn + j * 16 + fr;
            #pragma unroll
            for (int r = 0; r < 4; ++r) {
                const int row = m0 + wm + i * 16 + quad * 4 + r;
                const long idx = (long)row * N + col;
                float v = acc[i][j][r];
                if (EPI == 0) {
                    outF[idx] = v;
                } else if (EPI == 1) {
                    v = fmaxf(v + bias[col], 0.f);
                    outB[idx] = __float2bfloat16(v);
                } else if (EPI == 2) {
                    outF[idx] = v + bias[col] + res[idx];
                } else {
                    outB[idx] = __float2bfloat16(v);
                }
            }
        }
    }
}

// ---------------- MFMA causal flash attention ---------------------------------
struct alignas(8) bh4s { bf16 a, b, c, d; };

__global__ __launch_bounds__(256, 2) void attn_mfma_kernel(
        const bf16* __restrict__ qkv, bf16* __restrict__ ab) {
    __shared__ bf16 Kt[64][72];
    __shared__ bf16 Vt[64][72];
    __shared__ bf16 Pb[4][16][72];

    const int tid  = threadIdx.x;
    const int bh   = blockIdx.x;
    const int b    = bh / HH, h = bh % HH;
    const int w    = tid >> 6;
    const int ln   = tid & 63;
    const int ln15 = ln & 15;
    const int quad = ln >> 4;

    short8 qf[4][2];
    #pragma unroll
    for (int i = 0; i < 4; ++i) {
        const long tok = (long)b * TT + w * 16 + i * 64 + ln15;
        const bf16* p = qkv + tok * NQKV + h * HSZ + quad * 8;
        qf[i][0] = *(const short8*)p;
        qf[i][1] = *(const short8*)(p + 32);
    }

    f32x4 accO[4][4];
    float mrow[4][4], lrow[4][4];
    #pragma unroll
    for (int i = 0; i < 4; ++i) {
        #pragma unroll
        for (int j = 0; j < 4; ++j) accO[i][j] = (f32x4){0.f, 0.f, 0.f, 0.f};
        #pragma unroll
        for (int r = 0; r < 4; ++r) { mrow[i][r] = -1e30f; lrow[i][r] = 0.f; }
    }

    for (int sidx = 0; sidx < 4; ++sidx) {
        const int s0 = sidx * 64;
        __syncthreads();
        {
            const bf16* kg = qkv + (long)(b * TT + s0) * NQKV + CC + h * HSZ;
            #pragma unroll
            for (int it = 0; it < 2; ++it) {
                const int u = tid + it * 256;
                const int r = u >> 3, c = (u & 7) * 8;
                *(uint4*)&Kt[r][c] = *(const uint4*)(kg + (long)r * NQKV + c);
            }
            const bf16* vg = qkv + (long)(b * TT + s0) * NQKV + 2 * CC + h * HSZ;
            const int s = tid & 63;
            #pragma unroll
            for (int it = 0; it < 4; ++it) {
                const int dq = (tid >> 6) + it * 4;
                const bh4s vv = *(const bh4s*)(vg + (long)s * NQKV + dq * 4);
                Vt[dq * 4 + 0][s] = vv.a;
                Vt[dq * 4 + 1][s] = vv.b;
                Vt[dq * 4 + 2][s] = vv.c;
                Vt[dq * 4 + 3][s] = vv.d;
            }
        }
        __syncthreads();

        for (int i = sidx; i < 4; ++i) {
            const int rb = w * 16 + i * 64;
            f32x4 S[4];
            #pragma unroll
            for (int jt = 0; jt < 4; ++jt) S[jt] = (f32x4){0.f, 0.f, 0.f, 0.f};
            #pragma unroll
            for (int ks = 0; ks < 2; ++ks) {
                #pragma unroll
                for (int jt = 0; jt < 4; ++jt) {
                    const short8 kf = *(const short8*)&Kt[jt * 16 + ln15][ks * 32 + quad * 8];
                    S[jt] = __builtin_amdgcn_mfma_f32_16x16x32_bf16(qf[i][ks], kf, S[jt], 0, 0, 0);
                }
            }
            float rmax[4];
            #pragma unroll
            for (int r = 0; r < 4; ++r) rmax[r] = -1e30f;
            #pragma unroll
            for (int jt = 0; jt < 4; ++jt) {
                #pragma unroll
                for (int r = 0; r < 4; ++r) {
                    float v = S[jt][r] * 0.125f;
                    if (i == sidx) {
                        const int col = s0 + jt * 16 + ln15;
                        const int row = rb + quad * 4 + r;
                        if (col > row) v = -1e30f;
                    }
                    S[jt][r] = v;
                    rmax[r] = fmaxf(rmax[r], v);
                }
            }
            #pragma unroll
            for (int off = 1; off < 16; off <<= 1)
                #pragma unroll
                for (int r = 0; r < 4; ++r)
                    rmax[r] = fmaxf(rmax[r], __shfl_xor(rmax[r], off, 64));

            float alpha[4], rsum[4];
            #pragma unroll
            for (int r = 0; r < 4; ++r) {
                const float mn = fmaxf(mrow[i][r], rmax[r]);
                alpha[r] = __expf(mrow[i][r] - mn);
                mrow[i][r] = mn;
                rsum[r] = 0.f;
            }
            #pragma unroll
            for (int jt = 0; jt < 4; ++jt)
                #pragma unroll
                for (int r = 0; r < 4; ++r) {
                    const float p = __expf(S[jt][r] - mrow[i][r]);
                    S[jt][r] = p;
                    rsum[r] += p;
                }
            #pragma unroll
            for (int off = 1; off < 16; off <<= 1)
                #pragma unroll
                for (int r = 0; r < 4; ++r)
                    rsum[r] += __shfl_xor(rsum[r], off, 64);
            #pragma unroll
            for (int r = 0; r < 4; ++r)
                lrow[i][r] = lrow[i][r] * alpha[r] + rsum[r];
            #pragma unroll
            for (int jt = 0; jt < 4; ++jt)
                #pragma unroll
                for (int r = 0; r < 4; ++r)
                    accO[i][jt][r] *= alpha[r];

            #pragma unroll
            for (int jt = 0; jt < 4; ++jt)
                #pragma unroll
                for (int r = 0; r < 4; ++r)
                    Pb[w][quad * 4 + r][jt * 16 + ln15] = __float2bfloat16(S[jt][r]);
            const short8 pf0 = *(const short8*)&Pb[w][ln15][quad * 8];
            const short8 pf1 = *(const short8*)&Pb[w][ln15][32 + quad * 8];
            #pragma unroll
            for (int jt = 0; jt < 4; ++jt) {
                const short8 vf0 = *(const short8*)&Vt[jt * 16 + ln15][quad * 8];
                const short8 vf1 = *(const short8*)&Vt[jt * 16 + ln15][32 + quad * 8];
                accO[i][jt] = __builtin_amdgcn_mfma_f32_16x16x32_bf16(pf0, vf0, accO[i][jt], 0, 0, 0);
                accO[i][jt] = __builtin_amdgcn_mfma_f32_16x16x32_bf16(pf1, vf1, accO[i][jt], 0, 0, 0);
            }
        }
    }

    #pragma unroll
    for (int i = 0; i < 4; ++i) {
        const int rb = w * 16 + i * 64;
        float inv[4];
        #pragma unroll
        for (int r = 0; r < 4; ++r) inv[r] = 1.0f / lrow[i][r];
        #pragma unroll
        for (int jt = 0; jt < 4; ++jt)
            #pragma unroll
            for (int r = 0; r < 4; ++r)
                Pb[w][quad * 4 + r][jt * 16 + ln15] = __float2bfloat16(accO[i][jt][r] * inv[r]);
        #pragma unroll
        for (int it = 0; it < 2; ++it) {
            const int u = ln + it * 64;
            const int row = u >> 3, ch = (u & 7) * 8;
            const long tok = (long)b * TT + rb + row;
            *(uint4*)(ab + tok * CC + h * HSZ + ch) = *(const uint4*)&Pb[w][row][ch];
        }
    }
}

// ---------------- launcher ----------------------------------------------------
extern "C" void kernel_launch(void* const* d_in, const int* in_sizes, int n_in,
                              void* d_out, int out_size, void* d_ws, size_t ws_size,
                              hipStream_t stream) {
    const float* x   = (const float*)d_in[0];
    const float* Wq  = (const float*)d_in[1];
    const float* Wk  = (const float*)d_in[2];
    const float* Wv  = (const float*)d_in[3];
    const float* Wo  = (const float*)d_in[4];
    const float* bo  = (const float*)d_in[5];
    const float* W1  = (const float*)d_in[6];
    const float* b1  = (const float*)d_in[7];
    const float* W2  = (const float*)d_in[8];
    const float* b2  = (const float*)d_in[9];
    const float* g1  = (const float*)d_in[10];
    const float* be1 = (const float*)d_in[11];
    const float* g2  = (const float*)d_in[12];
    const float* be2 = (const float*)d_in[13];

    float* out = (float*)d_out;
    char*  ws  = (char*)d_ws;

    const size_t qkvBytes = (size_t)NTOK * NQKV * 4;
    const size_t actOff   = (qkvBytes + 255) & ~(size_t)255;
    const size_t actBytes = (size_t)NTOK * CC * 2;
    size_t wOff = (actOff + actBytes + 255) & ~(size_t)255;

    bf16* qkvb = (bf16*)ws;
    bf16* ff1  = (bf16*)ws;
    bf16* actb = (bf16*)(ws + actOff);

    bf16* WcatT = (bf16*)(ws + wOff); wOff += (size_t)NQKV * CC * 2 + 256;
    bf16* WoT   = (bf16*)(ws + ((wOff + 255) & ~(size_t)255)); wOff = ((wOff + 255) & ~(size_t)255) + (size_t)CC * CC * 2;
    bf16* W1T   = (bf16*)(ws + ((wOff + 255) & ~(size_t)255)); wOff = ((wOff + 255) & ~(size_t)255) + (size_t)DFF * CC * 2;
    bf16* W2T   = (bf16*)(ws + ((wOff + 255) & ~(size_t)255));

    pack_qkv_w      <<<NQKV, CC, 0, stream>>>(Wq, Wk, Wv, WcatT);
    transpose_to_bf16<<<dim3(CC / 32,  CC / 32),  256, 0, stream>>>(Wo, WoT, CC,  CC);
    transpose_to_bf16<<<dim3(DFF / 32, CC / 32),  256, 0, stream>>>(W1, W1T, CC,  DFF);
    transpose_to_bf16<<<dim3(CC / 32,  DFF / 32), 256, 0, stream>>>(W2, W2T, DFF, CC);

    ln_bf16_kernel<<<NTOK / RPB, CC, 0, stream>>>(x, g1, be1, actb);
    gemm_bt<CC, 3><<<dim3(NTOK / 128, NQKV / 128), 256, 0, stream>>>(
        actb, WcatT, nullptr, nullptr, nullptr, qkvb, NQKV);
    attn_mfma_kernel<<<BB * HH, 256, 0, stream>>>(qkvb, actb);
    gemm_bt<CC, 2><<<dim3(NTOK / 128, CC / 128), 256, 0, stream>>>(
        actb, WoT, bo, x, out, nullptr, CC);

    ln_bf16_kernel<<<NTOK / RPB, CC, 0, stream>>>(out, g2, be2, actb);
    gemm_bt<CC, 1><<<dim3(NTOK / 128, DFF / 128), 256, 0, stream>>>(
        actb, W1T, b1, nullptr, nullptr, ff1, DFF);
    gemm_bt<DFF, 2><<<dim3(NTOK / 128, CC / 128), 256, 0, stream>>>(
        ff1, W2T, b2, out, out, nullptr, CC);
}